// Round 1
// 298.813 us; speedup vs baseline: 1.0825x; 1.0825x over previous
//
#include <hip/hip_runtime.h>
#include <cstdint>
#include <cstddef>

#define B_ROWS 16384
#define D_COLS 2048
#define NCLS   1000
#define NBUCK  1024   // top-10-bit buckets for the shuffle rank sort

typedef float f4v __attribute__((ext_vector_type(4)));

__device__ __forceinline__ void nt_store_f4(float4* p, float4 v) {
    __builtin_nontemporal_store(*reinterpret_cast<f4v*>(&v),
                                reinterpret_cast<f4v*>(p));
}

// ---------------- Threefry-2x32 (JAX-compatible), host+device ----------------
__host__ __device__ __forceinline__ uint32_t rotl32(uint32_t v, int r) {
    return (v << r) | (v >> (32 - r));
}

__host__ __device__ inline void tf2x32(uint32_t k0, uint32_t k1,
                                       uint32_t x0, uint32_t x1,
                                       uint32_t& o0, uint32_t& o1) {
    uint32_t ks0 = k0, ks1 = k1, ks2 = k0 ^ k1 ^ 0x1BD11BDAu;
    x0 += ks0; x1 += ks1;
    x0 += x1; x1 = rotl32(x1, 13); x1 ^= x0;
    x0 += x1; x1 = rotl32(x1, 15); x1 ^= x0;
    x0 += x1; x1 = rotl32(x1, 26); x1 ^= x0;
    x0 += x1; x1 = rotl32(x1, 6);  x1 ^= x0;
    x0 += ks1; x1 += ks2 + 1u;
    x0 += x1; x1 = rotl32(x1, 17); x1 ^= x0;
    x0 += x1; x1 = rotl32(x1, 29); x1 ^= x0;
    x0 += x1; x1 = rotl32(x1, 16); x1 ^= x0;
    x0 += x1; x1 = rotl32(x1, 24); x1 ^= x0;
    x0 += ks2; x1 += ks0 + 2u;
    x0 += x1; x1 = rotl32(x1, 13); x1 ^= x0;
    x0 += x1; x1 = rotl32(x1, 15); x1 ^= x0;
    x0 += x1; x1 = rotl32(x1, 26); x1 ^= x0;
    x0 += x1; x1 = rotl32(x1, 6);  x1 ^= x0;
    x0 += ks0; x1 += ks1 + 3u;
    x0 += x1; x1 = rotl32(x1, 17); x1 ^= x0;
    x0 += x1; x1 = rotl32(x1, 29); x1 ^= x0;
    x0 += x1; x1 = rotl32(x1, 16); x1 ^= x0;
    x0 += x1; x1 = rotl32(x1, 24); x1 ^= x0;
    x0 += ks1; x1 += ks2 + 4u;
    x0 += x1; x1 = rotl32(x1, 13); x1 ^= x0;
    x0 += x1; x1 = rotl32(x1, 15); x1 ^= x0;
    x0 += x1; x1 = rotl32(x1, 26); x1 ^= x0;
    x0 += x1; x1 = rotl32(x1, 6);  x1 ^= x0;
    x0 += ks2; x1 += ks0 + 5u;
    o0 = x0; o1 = x1;
}

// XLA ErfInv (f32, Giles approximation)
__device__ __forceinline__ float erfinv_f(float x) {
    float w = -log1pf(-x * x);
    float p;
    if (w < 5.0f) {
        w -= 2.5f;
        p = 2.81022636e-08f;
        p = fmaf(p, w, 3.43273939e-07f);
        p = fmaf(p, w, -3.5233877e-06f);
        p = fmaf(p, w, -4.39150654e-06f);
        p = fmaf(p, w, 0.00021858087f);
        p = fmaf(p, w, -0.00125372503f);
        p = fmaf(p, w, -0.00417768164f);
        p = fmaf(p, w, 0.246640727f);
        p = fmaf(p, w, 1.50140941f);
    } else {
        w = sqrtf(w) - 3.0f;
        p = -0.000200214257f;
        p = fmaf(p, w, 0.000100950558f);
        p = fmaf(p, w, 0.00134934322f);
        p = fmaf(p, w, -0.00367342844f);
        p = fmaf(p, w, 0.00573950773f);
        p = fmaf(p, w, -0.0076224613f);
        p = fmaf(p, w, 0.00943887047f);
        p = fmaf(p, w, 1.00167406f);
        p = fmaf(p, w, 2.83297682f);
    }
    return p * x;
}

// ------------------------------- kernels -------------------------------------

// y histogram + threefry bits for both shuffle rounds + bucket histograms.
__global__ void k_bits_hist(const int* __restrict__ y, int* __restrict__ cnt,
                            uint32_t* __restrict__ kAbits, uint32_t* __restrict__ kBbits,
                            int* __restrict__ bhA, int* __restrict__ bhB,
                            uint32_t s1_0, uint32_t s1_1,
                            uint32_t s2_0, uint32_t s2_1) {
    int i = blockIdx.x * 256 + threadIdx.x;
    atomicAdd(&cnt[y[i]], 1);
    uint32_t a, b;
    tf2x32(s1_0, s1_1, 0u, (uint32_t)i, a, b);
    uint32_t bitsA = a ^ b;
    kAbits[i] = bitsA;
    atomicAdd(&bhA[bitsA >> 22], 1);
    tf2x32(s2_0, s2_1, 0u, (uint32_t)i, a, b);
    uint32_t bitsB = a ^ b;
    kBbits[i] = bitsB;
    atomicAdd(&bhB[bitsB >> 22], 1);
}

// three independent 1024-wide exclusive prefix sums (cnt, bhA, bhB)
__global__ void k_prefix3(const int* __restrict__ cnt, int* __restrict__ rowstart,
                          const int* __restrict__ bhA, int* __restrict__ bsA,
                          const int* __restrict__ bhB, int* __restrict__ bsB) {
    __shared__ int sm[1024];
    int t = threadIdx.x;
    const int* src; int* dst; int n;
    if (blockIdx.x == 0)      { src = cnt; dst = rowstart; n = NCLS; }
    else if (blockIdx.x == 1) { src = bhA; dst = bsA;      n = NBUCK; }
    else                      { src = bhB; dst = bsB;      n = NBUCK; }
    int v = (t < n) ? src[t] : 0;
    sm[t] = v;
    for (int off = 1; off < 1024; off <<= 1) {
        __syncthreads();
        int u = (t >= off) ? sm[t - off] : 0;
        __syncthreads();
        sm[t] += u;
    }
    if (t < n) dst[t] = sm[t] - v;
}

// bucket rows by class + bucket indices by shuffle-key bucket (both rounds)
__global__ void k_scatter_all(const int* __restrict__ y,
                              const uint32_t* __restrict__ kAbits,
                              const uint32_t* __restrict__ kBbits,
                              const int* __restrict__ rowstart, int* __restrict__ rowpos,
                              int* __restrict__ rowlist,
                              const int* __restrict__ bsA, int* __restrict__ bposA,
                              int* __restrict__ memA,
                              const int* __restrict__ bsB, int* __restrict__ bposB,
                              int* __restrict__ memB) {
    int i = blockIdx.x * 256 + threadIdx.x;
    int c = y[i];
    int p = atomicAdd(&rowpos[c], 1);
    rowlist[rowstart[c] + p] = i;
    uint32_t bA = kAbits[i] >> 22;
    p = atomicAdd(&bposA[bA], 1);
    memA[bsA[bA] + p] = i;
    uint32_t bB = kBbits[i] >> 22;
    p = atomicAdd(&bposB[bB], 1);
    memB[bsB[bB] + p] = i;
}

// Fused mid-stage. blocks [0,64): bucketed rank for both shuffle rounds
// (latency-bound, hides under the BW-bound class blocks). blocks [64,2064):
// per-class sum/sumsq over 1024 cols + noise generation fused in-register
// (s/sq never touch memory — the round-trip through f32 memory was lossless,
// so computing noise from the register copies is bit-identical).
__global__ void __launch_bounds__(256) k_mid(
        const float* __restrict__ x, const int* __restrict__ rowlist,
        const int* __restrict__ rowstart, const int* __restrict__ cnt,
        float* __restrict__ noise, uint32_t nk0, uint32_t nk1,
        const uint32_t* __restrict__ kAbits, const uint32_t* __restrict__ kBbits,
        const int* __restrict__ bsA, const int* __restrict__ bhA,
        const int* __restrict__ memA,
        const int* __restrict__ bsB, const int* __restrict__ bhB,
        const int* __restrict__ memB,
        int* __restrict__ x1, int* __restrict__ rank2) {
    int bid = blockIdx.x, t = threadIdx.x;
    if (bid >= 64) {
        // ---- class sums + fused noise ----
        int cb = bid - 64;
        int c = cb >> 1, h = cb & 1;
        int start = rowstart[c], n = cnt[c];
        const float4* xb = (const float4*)x + (size_t)h * 256 + t;
        float sx=0,sy=0,sz=0,sw=0, qx=0,qy=0,qz=0,qw=0;
        int r = 0;
        for (; r + 2 <= n; r += 2) {
            int row0 = rowlist[start + r];
            int row1 = rowlist[start + r + 1];
            float4 a = xb[(size_t)row0 * 512];
            float4 b = xb[(size_t)row1 * 512];
            sx += a.x; sy += a.y; sz += a.z; sw += a.w;
            qx = fmaf(a.x, a.x, qx); qy = fmaf(a.y, a.y, qy);
            qz = fmaf(a.z, a.z, qz); qw = fmaf(a.w, a.w, qw);
            sx += b.x; sy += b.y; sz += b.z; sw += b.w;
            qx = fmaf(b.x, b.x, qx); qy = fmaf(b.y, b.y, qy);
            qz = fmaf(b.z, b.z, qz); qw = fmaf(b.w, b.w, qw);
        }
        if (r < n) {
            int row = rowlist[start + r];
            float4 a = xb[(size_t)row * 512];
            sx += a.x; sy += a.y; sz += a.z; sw += a.w;
            qx = fmaf(a.x, a.x, qx); qy = fmaf(a.y, a.y, qy);
            qz = fmaf(a.z, a.z, qz); qw = fmaf(a.w, a.w, qw);
        }
        // noise for this thread's 4 columns (same math as old k_noise,
        // same per-element threefry counter n = c*2048 + col)
        float sarr[4] = {sx, sy, sz, sw};
        float qarr[4] = {qx, qy, qz, qw};
        float oarr[4];
        float cf = (float)n;
        uint32_t nbase = (uint32_t)(c * 2048 + h * 1024 + t * 4);
        #pragma unroll
        for (int j = 0; j < 4; ++j) {
            uint32_t b1, b2;
            tf2x32(nk0, nk1, 0u, nbase + (uint32_t)j, b1, b2);
            uint32_t bits = b1 ^ b2;
            float f = __uint_as_float((bits >> 9) | 0x3f800000u) - 1.0f;
            const float LO = -0.99999994f;
            float u = fmaxf(LO, fmaf(f, 2.0f, LO));
            float nrm = 1.41421356f * erfinv_f(u);
            float m = sarr[j] / cf;
            float var = (qarr[j] - cf * m * m) / (cf - 1.0f);
            float sd = sqrtf(fmaxf(var, 0.0f));
            oarr[j] = fmaf(sd, nrm, m);
        }
        int o = c * 512 + h * 256 + t;
        ((float4*)noise)[o] = make_float4(oarr[0], oarr[1], oarr[2], oarr[3]);
    } else {
        // ---- bucketed rank for both rounds (old k_rankAB) ----
        int i = bid * 256 + t;
        uint32_t a = kAbits[i];
        {
            uint32_t b = a >> 22;
            int st = bsA[b], n = bhA[b];
            int ca = 0;
            for (int k = 0; k < n; k++) {
                int m = memA[st + k];
                uint32_t mb = kAbits[m];
                ca += (mb < a) || (mb == a && m < i);
            }
            x1[st + ca] = i;       // round-1 scatter fused (values were arange)
        }
        uint32_t c = kBbits[i];
        {
            uint32_t b = c >> 22;
            int st = bsB[b], n = bhB[b];
            int cb = 0;
            for (int k = 0; k < n; k++) {
                int m = memB[st + k];
                uint32_t mb = kBbits[m];
                cb += (mb < c) || (mb == c && m < i);
            }
            rank2[i] = st + cb;
        }
    }
}

// round 2 scatter fused with gather: newY[rank2[i]] = y[x1[i]]; f32 tail of d_out
__global__ void k_scatter2(const int* __restrict__ y, const int* __restrict__ x1,
                           const int* __restrict__ rank2, int* __restrict__ newY,
                           float* __restrict__ outTail) {
    int i = blockIdx.x * 256 + threadIdx.x;
    int v = y[x1[i]];
    int j = rank2[i];
    newY[j] = v;
    outTail[j] = (float)v;
}

// blend. x is L3-resident from k_mid's pass (134 MB + 8 MB noise < 256 MB L3);
// non-temporal out-stores keep it that way instead of evicting it.
__global__ void __launch_bounds__(256) k_final(
        const float* __restrict__ x, const float* __restrict__ noise,
        const int* __restrict__ newY, float* __restrict__ out) {
    int b = blockIdx.x, t = threadIdx.x;
    int ny = newY[b];
    const float4* xr = (const float4*)x + (size_t)b * (D_COLS / 4);
    const float4* nr = (const float4*)noise + (size_t)ny * (D_COLS / 4);
    float4* orow = (float4*)out + (size_t)b * (D_COLS / 4);
    float4 xa = xr[t], na = nr[t];
    float4 o;
    o.x = fmaf(0.1f, na.x, 0.9f * xa.x);
    o.y = fmaf(0.1f, na.y, 0.9f * xa.y);
    o.z = fmaf(0.1f, na.z, 0.9f * xa.z);
    o.w = fmaf(0.1f, na.w, 0.9f * xa.w);
    nt_store_f4(&orow[t], o);
    xa = xr[t + 256]; na = nr[t + 256];
    o.x = fmaf(0.1f, na.x, 0.9f * xa.x);
    o.y = fmaf(0.1f, na.y, 0.9f * xa.y);
    o.z = fmaf(0.1f, na.z, 0.9f * xa.z);
    o.w = fmaf(0.1f, na.w, 0.9f * xa.w);
    nt_store_f4(&orow[t + 256], o);
}

// ------------------------------- launcher ------------------------------------
extern "C" void kernel_launch(void* const* d_in, const int* in_sizes, int n_in,
                              void* d_out, int out_size, void* d_ws, size_t ws_size,
                              hipStream_t stream) {
    const float* x = (const float*)d_in[0];
    const int* y = (const int*)d_in[1];
    float* out = (float*)d_out;
    float* outTail = out + (size_t)B_ROWS * D_COLS;

    char* ws = (char*)d_ws;
    float* noise = (float*)(ws + 16384000);            // 8,192,000 B
    int* ints = (int*)(ws + 24576000);
    // --- zeroed region (one memset): 6096 ints ---
    int* cnt      = ints;            // 1000
    int* rowpos   = ints + 1000;     // 1000
    int* bhA      = ints + 2000;     // 1024
    int* bposA    = ints + 3024;     // 1024
    int* bhB      = ints + 4048;     // 1024
    int* bposB    = ints + 5072;     // 1024
    // --- non-zeroed ---
    int* rowstart = ints + 6096;     // 1000
    int* bsA      = ints + 7096;     // 1024
    int* bsB      = ints + 8120;     // 1024
    int* rowlist  = ints + 9144;     // 16384
    int* memA     = ints + 25528;    // 16384
    int* memB     = ints + 41912;    // 16384
    int* x1       = ints + 58296;    // 16384
    int* rank2    = ints + 74680;    // 16384
    int* newY     = ints + 91064;    // 16384
    uint32_t* kAbits = (uint32_t*)(ints + 107448);     // 16384
    uint32_t* kBbits = (uint32_t*)(ints + 123832);     // 16384

    hipMemsetAsync(cnt, 0, 6096 * sizeof(int), stream);

    // Host-side key derivation (jax.random.key(42), partitionable/foldlike split)
    uint32_t nk0, nk1, pk0, pk1, pn0, pn1, s1_0, s1_1, s2_0, s2_1;
    tf2x32(0u, 42u, 0u, 0u, nk0, nk1);    // nk (noise key)
    tf2x32(0u, 42u, 0u, 1u, pk0, pk1);    // pk (perm key)
    tf2x32(pk0, pk1, 0u, 0u, pn0, pn1);   // pk after round-1 split
    tf2x32(pk0, pk1, 0u, 1u, s1_0, s1_1); // round-1 subkey
    tf2x32(pn0, pn1, 0u, 1u, s2_0, s2_1); // round-2 subkey

    k_bits_hist<<<64, 256, 0, stream>>>(y, cnt, kAbits, kBbits, bhA, bhB,
                                        s1_0, s1_1, s2_0, s2_1);
    k_prefix3<<<3, 1024, 0, stream>>>(cnt, rowstart, bhA, bsA, bhB, bsB);
    k_scatter_all<<<64, 256, 0, stream>>>(y, kAbits, kBbits, rowstart, rowpos,
                                          rowlist, bsA, bposA, memA,
                                          bsB, bposB, memB);
    k_mid<<<2 * NCLS + 64, 256, 0, stream>>>(x, rowlist, rowstart, cnt,
                                             noise, nk0, nk1,
                                             kAbits, kBbits,
                                             bsA, bhA, memA,
                                             bsB, bhB, memB, x1, rank2);
    k_scatter2<<<64, 256, 0, stream>>>(y, x1, rank2, newY, outTail);
    k_final<<<16384, 256, 0, stream>>>(x, noise, newY, out);
}